// Round 2
// baseline (901.817 us; speedup 1.0000x reference)
//
#include <hip/hip_runtime.h>

// ---------------------------------------------------------------------------
// PositionalEncoding: out[b,l,d] = x[b,l,d] + pe[l,d]
//   counts = cumsum over l of TAB[rot[l], case[l]]          (exact small ints)
//   pe[l, 2k]   = sin(counts_x[l] * div_term[k])
//   pe[l, 2k+1] = cos(counts_y[l] * div_term[k])
// B=16, L=4096, D=2048.  Memory-bound: 0.5 GiB in + 0.5 GiB out.
//
// 3-kernel plan:
//   1. scan_kernel   : (L,) cumsum of action deltas            (~10 us, 1 blk)
//   2. pe_fill_kernel: materialize pe (L*D floats = 32 MiB) in ws (~15 us)
//   3. add_kernel    : pure streaming out = x + pe — the exact pattern the
//      harness fill / m13 copy run at 6.3+ TB/s.  Each thread's 8 quads are
//      b-strided so its pe quad index is loop-invariant (1 pe load, 8 x loads
//      in flight, 8 stores).  pe logical reads = 64 MiB -> L2/LLC.
// Fallback: if ws can't hold counts+pe, use the verified fused kernel.
// ---------------------------------------------------------------------------

#define B_  16
#define L_  4096
#define D_  2048
#define D4_ (D_ / 4)   // 512 float4 groups per row

typedef float f32x4 __attribute__((ext_vector_type(4)));

__constant__ int c_TAB[8][5][2] = {
    { { 1,  0}, {-1,  0}, { 0, -1}, { 0,  1}, {0, 0} },
    { { 1,  1}, {-1, -1}, { 1, -1}, {-1,  1}, {0, 0} },
    { { 0,  1}, { 0, -1}, { 1,  0}, {-1,  0}, {0, 0} },
    { {-1,  1}, { 1, -1}, { 1,  1}, {-1, -1}, {0, 0} },
    { {-1,  0}, { 1,  0}, { 0,  1}, { 0, -1}, {0, 0} },
    { {-1, -1}, { 1,  1}, {-1,  1}, { 1, -1}, {0, 0} },
    { { 0, -1}, { 0,  1}, {-1,  0}, { 1,  0}, {0, 0} },
    { { 1, -1}, {-1,  1}, {-1, -1}, { 1,  1}, {0, 0} },
};

// ---------------------------------------------------------------------------
// Kernel 1: cumsum of deltas over L.  One block, 256 threads, 16 elems per
// thread: per-thread serial scan, Hillis-Steele block scan of per-thread
// sums in LDS, write inclusive counts as float2.  (verified correct)
// ---------------------------------------------------------------------------
__global__ __launch_bounds__(256) void scan_kernel(
    const int* __restrict__ action,   // (L, 3) int32
    float2* __restrict__ counts)      // (L,) float2  -> d_ws
{
    constexpr int NT = 256;
    constexpr int CHUNK = L_ / NT;    // 16
    __shared__ int2 sums[NT];

    const int t = threadIdx.x;
    const int base = t * CHUNK;

    int dx[CHUNK], dy[CHUNK];
    int sx = 0, sy = 0;
    #pragma unroll
    for (int j = 0; j < CHUNK; ++j) {
        const int l  = base + j;
        const int i0 = action[l * 3 + 0];
        const int i1 = action[l * 3 + 1];
        int r        = action[l * 3 + 2];
        r = ((r % 8) + 8) % 8;
        const int c = (i0 == 1) ? 0
                    : (i0 == -1) ? 1
                    : (i1 == 1) ? 2
                    : (i1 == -1) ? 3 : 4;
        sx += c_TAB[r][c][0];
        sy += c_TAB[r][c][1];
        dx[j] = sx;               // inclusive within this thread's chunk
        dy[j] = sy;
    }
    sums[t] = make_int2(sx, sy);
    __syncthreads();

    // Hillis-Steele inclusive scan over the 256 per-thread sums.
    for (int off = 1; off < NT; off <<= 1) {
        int2 v   = sums[t];
        int2 add = (t >= off) ? sums[t - off] : make_int2(0, 0);
        __syncthreads();
        sums[t] = make_int2(v.x + add.x, v.y + add.y);
        __syncthreads();
    }

    const int px = (t > 0) ? sums[t - 1].x : 0;
    const int py = (t > 0) ? sums[t - 1].y : 0;
    #pragma unroll
    for (int j = 0; j < CHUNK; ++j) {
        counts[base + j] = make_float2((float)(px + dx[j]), (float)(py + dy[j]));
    }
}

// ---------------------------------------------------------------------------
// Kernel 2: materialize pe quads into workspace.  One thread per (l, d4).
// 2^21 threads, 32 MiB written.  Off the streaming hot path.
// ---------------------------------------------------------------------------
__global__ __launch_bounds__(256) void pe_fill_kernel(
    const float2* __restrict__ counts,    // (L,)  {cx, cy}
    const float2* __restrict__ div2,      // (D/2,) viewed as (D/4,) float2
    f32x4* __restrict__ pe)               // (L*D/4,) quads
{
    const int tid = blockIdx.x * blockDim.x + threadIdx.x;   // [0, L*D/4)
    const int d4  = tid & (D4_ - 1);
    const int l   = tid >> 9;

    const float2 c  = counts[l];
    const float2 dt = div2[d4];   // div_term[2*d4], div_term[2*d4+1]

    f32x4 v;
    v.x = sinf(c.x * dt.x);
    v.y = cosf(c.y * dt.x);
    v.z = sinf(c.x * dt.y);
    v.w = cosf(c.y * dt.y);
    pe[tid] = v;
}

// ---------------------------------------------------------------------------
// Kernel 3: out = x + pe.  Pure 3-stream elementwise add, the proven-6.3TB/s
// pattern.  2^22 threads; each handles 8 quads at stride 2^22 quads (= 2
// batches), so (idx & 2^21-1) is invariant -> ONE pe load per thread.
// Chip-wide, each unroll step sweeps a contiguous 64 MiB window.
// ---------------------------------------------------------------------------
__global__ __launch_bounds__(256) void add_kernel(
    const f32x4* __restrict__ x,
    const f32x4* __restrict__ pe,
    f32x4* __restrict__ out)
{
    constexpr size_t STRIDE = (size_t)1 << 22;      // quads per sweep
    constexpr size_t PEMASK = ((size_t)1 << 21) - 1;
    const size_t tid = (size_t)blockIdx.x * blockDim.x + threadIdx.x;

    const f32x4 p = pe[tid & PEMASK];

    f32x4 v[8];
    #pragma unroll
    for (int j = 0; j < 8; ++j) {
        v[j] = x[tid + (size_t)j * STRIDE];
    }
    #pragma unroll
    for (int j = 0; j < 8; ++j) {
        out[tid + (size_t)j * STRIDE] = v[j] + p;
    }
}

// ---------------------------------------------------------------------------
// Fallback (verified round-1 kernel): fused pe-compute + add, used only if
// the workspace is too small to hold counts + pe.
// ---------------------------------------------------------------------------
__global__ __launch_bounds__(256) void pe_add_kernel(
    const float* __restrict__ x,          // (B, L, D)
    const float2* __restrict__ counts,    // (L,)  {cx, cy}
    const float2* __restrict__ div2,      // (D/2,) viewed as (D/4,) float2
    float* __restrict__ out)              // (B, L, D)
{
    const int tid = blockIdx.x * blockDim.x + threadIdx.x;   // [0, L*D/4)
    const int d4  = tid & (D4_ - 1);
    const int l   = tid >> 9;                                // tid / 512

    const float2 c  = counts[l];
    const float2 dt = div2[d4];

    f32x4 pe;
    pe.x = sinf(c.x * dt.x);
    pe.y = cosf(c.y * dt.x);
    pe.z = sinf(c.x * dt.y);
    pe.w = cosf(c.y * dt.y);

    const f32x4* __restrict__ xp = (const f32x4*)x + tid;
    f32x4* __restrict__       op = (f32x4*)out + tid;
    constexpr size_t stride4 = (size_t)L_ * D_ / 4;

    #pragma unroll
    for (int g = 0; g < 2; ++g) {
        f32x4 v[8];
        #pragma unroll
        for (int j = 0; j < 8; ++j) {
            v[j] = __builtin_nontemporal_load(xp + (size_t)(g * 8 + j) * stride4);
        }
        #pragma unroll
        for (int j = 0; j < 8; ++j) {
            f32x4 ov = v[j] + pe;
            __builtin_nontemporal_store(ov, op + (size_t)(g * 8 + j) * stride4);
        }
    }
}

extern "C" void kernel_launch(void* const* d_in, const int* in_sizes, int n_in,
                              void* d_out, int out_size, void* d_ws, size_t ws_size,
                              hipStream_t stream) {
    const float* x        = (const float*)d_in[0];   // (16, 4096, 2048) fp32
    const int*   action   = (const int*)d_in[1];     // (4096, 3) int32
    const float* div_term = (const float*)d_in[2];   // (1024,) fp32
    float*       out      = (float*)d_out;

    float2* counts = (float2*)d_ws;                  // 4096 * 8 B = 32 KiB
    const size_t PE_OFF   = 32768;                   // bytes
    const size_t PE_BYTES = (size_t)L_ * D_ * 4;     // 32 MiB of pe quads
    f32x4*  pe     = (f32x4*)((char*)d_ws + PE_OFF);

    scan_kernel<<<1, 256, 0, stream>>>(action, counts);

    if (ws_size >= PE_OFF + PE_BYTES) {
        const int peQuads = (L_ * D_) / 4;           // 2^21
        pe_fill_kernel<<<peQuads / 256, 256, 0, stream>>>(
            counts, (const float2*)div_term, pe);

        const int addThreads = (B_ * L_ * D_ / 4) / 8;   // 2^22
        add_kernel<<<addThreads / 256, 256, 0, stream>>>(
            (const f32x4*)x, pe, (f32x4*)out);
    } else {
        const int total4 = (L_ * D_) / 4;
        pe_add_kernel<<<total4 / 256, 256, 0, stream>>>(
            x, counts, (const float2*)div_term, out);
    }
}

// Round 3
// 862.206 us; speedup vs baseline: 1.0459x; 1.0459x over previous
//
#include <hip/hip_runtime.h>

// ---------------------------------------------------------------------------
// PositionalEncoding: out[b,l,d] = x[b,l,d] + pe[l,d]
//   counts = cumsum over l of TAB[rot[l], case[l]]          (exact small ints)
//   pe[l, 2k]   = sin(counts_x[l] * div_term[k])
//   pe[l, 2k+1] = cos(counts_y[l] * div_term[k])
// B=16, L=4096, D=2048.  Memory-bound: 0.5 GiB in + 0.5 GiB out
// -> streaming roofline ~170 us at 6.3 TB/s.
//
// Measured history: fused 2-kernel (r1) = 865 us total incl. ~680 us harness
// poison fills -> controllable ~185 us.  Materialized-pe 3-kernel (r2) = 902
// (regression: extra 64 MiB round trip + launch).  This version: fused, with
// a 16-deep nontemporal load batch for max memory-level parallelism.
// ---------------------------------------------------------------------------

#define B_  16
#define L_  4096
#define D_  2048
#define D4_ (D_ / 4)   // 512 float4 groups per row

typedef float f32x4 __attribute__((ext_vector_type(4)));

__constant__ int c_TAB[8][5][2] = {
    { { 1,  0}, {-1,  0}, { 0, -1}, { 0,  1}, {0, 0} },
    { { 1,  1}, {-1, -1}, { 1, -1}, {-1,  1}, {0, 0} },
    { { 0,  1}, { 0, -1}, { 1,  0}, {-1,  0}, {0, 0} },
    { {-1,  1}, { 1, -1}, { 1,  1}, {-1, -1}, {0, 0} },
    { {-1,  0}, { 1,  0}, { 0,  1}, { 0, -1}, {0, 0} },
    { {-1, -1}, { 1,  1}, {-1,  1}, { 1, -1}, {0, 0} },
    { { 0, -1}, { 0,  1}, {-1,  0}, { 1,  0}, {0, 0} },
    { { 1, -1}, {-1,  1}, {-1, -1}, { 1,  1}, {0, 0} },
};

// ---------------------------------------------------------------------------
// Kernel 1: cumsum of deltas over L.  One block, 256 threads, 16 elems per
// thread: per-thread serial scan, Hillis-Steele block scan of per-thread
// sums in LDS, write inclusive counts as float2.  (verified correct, ~10 us)
// ---------------------------------------------------------------------------
__global__ __launch_bounds__(256) void scan_kernel(
    const int* __restrict__ action,   // (L, 3) int32
    float2* __restrict__ counts)      // (L,) float2  -> d_ws
{
    constexpr int NT = 256;
    constexpr int CHUNK = L_ / NT;    // 16
    __shared__ int2 sums[NT];

    const int t = threadIdx.x;
    const int base = t * CHUNK;

    int dx[CHUNK], dy[CHUNK];
    int sx = 0, sy = 0;
    #pragma unroll
    for (int j = 0; j < CHUNK; ++j) {
        const int l  = action ? base + j : 0;
        const int i0 = action[l * 3 + 0];
        const int i1 = action[l * 3 + 1];
        int r        = action[l * 3 + 2];
        r = ((r % 8) + 8) % 8;
        const int c = (i0 == 1) ? 0
                    : (i0 == -1) ? 1
                    : (i1 == 1) ? 2
                    : (i1 == -1) ? 3 : 4;
        sx += c_TAB[r][c][0];
        sy += c_TAB[r][c][1];
        dx[j] = sx;               // inclusive within this thread's chunk
        dy[j] = sy;
    }
    sums[t] = make_int2(sx, sy);
    __syncthreads();

    // Hillis-Steele inclusive scan over the 256 per-thread sums.
    for (int off = 1; off < NT; off <<= 1) {
        int2 v   = sums[t];
        int2 add = (t >= off) ? sums[t - off] : make_int2(0, 0);
        __syncthreads();
        sums[t] = make_int2(v.x + add.x, v.y + add.y);
        __syncthreads();
    }

    const int px = (t > 0) ? sums[t - 1].x : 0;
    const int py = (t > 0) ? sums[t - 1].y : 0;
    #pragma unroll
    for (int j = 0; j < CHUNK; ++j) {
        counts[base + j] = make_float2((float)(px + dx[j]), (float)(py + dy[j]));
    }
}

// ---------------------------------------------------------------------------
// Kernel 2: out = x + pe, fused.  One thread per (l, d-quad); pe fragment
// computed once in registers and reused across the 16 batches.
//   - 16 independent nontemporal dwordx4 loads issued back-to-back (deep
//     MLP; ~64 data VGPRs), then 16 add+nontemporal-store.
//   - nt bit keeps the 2x512MiB single-touch streams out of L2/LLC.
// ---------------------------------------------------------------------------
__global__ __launch_bounds__(256) void pe_add_kernel(
    const float* __restrict__ x,          // (B, L, D)
    const float2* __restrict__ counts,    // (L,)  {cx, cy}
    const float2* __restrict__ div2,      // (D/2,) viewed as (D/4,) float2
    float* __restrict__ out)              // (B, L, D)
{
    const int tid = blockIdx.x * blockDim.x + threadIdx.x;   // [0, L*D/4)
    const int d4  = tid & (D4_ - 1);
    const int l   = tid >> 9;                                // tid / 512

    const float2 c  = counts[l];
    const float2 dt = div2[d4];   // div_term[2*d4], div_term[2*d4+1]

    // elements d=4*d4 .. d+3 -> k0 = 2*d4, k1 = 2*d4+1
    f32x4 pe;
    pe.x = sinf(c.x * dt.x);
    pe.y = cosf(c.y * dt.x);
    pe.z = sinf(c.x * dt.y);
    pe.w = cosf(c.y * dt.y);

    const f32x4* __restrict__ xp = (const f32x4*)x + tid;
    f32x4* __restrict__       op = (f32x4*)out + tid;
    constexpr size_t stride4 = (size_t)L_ * D_ / 4;          // quads per batch

    f32x4 v[B_];
    #pragma unroll
    for (int j = 0; j < B_; ++j) {
        v[j] = __builtin_nontemporal_load(xp + (size_t)j * stride4);
    }
    #pragma unroll
    for (int j = 0; j < B_; ++j) {
        f32x4 ov = v[j] + pe;
        __builtin_nontemporal_store(ov, op + (size_t)j * stride4);
    }
}

extern "C" void kernel_launch(void* const* d_in, const int* in_sizes, int n_in,
                              void* d_out, int out_size, void* d_ws, size_t ws_size,
                              hipStream_t stream) {
    const float* x        = (const float*)d_in[0];   // (16, 4096, 2048) fp32
    const int*   action   = (const int*)d_in[1];     // (4096, 3) int32
    const float* div_term = (const float*)d_in[2];   // (1024,) fp32
    float*       out      = (float*)d_out;
    float2*      counts   = (float2*)d_ws;           // 4096 * 8 B = 32 KiB

    scan_kernel<<<1, 256, 0, stream>>>(action, counts);

    const int total4 = (L_ * D_) / 4;                // 2,097,152 threads
    pe_add_kernel<<<total4 / 256, 256, 0, stream>>>(
        x, counts, (const float2*)div_term, out);
}